// Round 6
// baseline (540.215 us; speedup 1.0000x reference)
//
#include <hip/hip_runtime.h>
#include <math.h>

// Problem dims (fixed by the reference)
#define S_DIM 4096
#define H_DIM 4096
#define HC_N 4
#define HD_DIM 16384   // HC_N * H_DIM
#define MIXN 24        // (2+HC)*HC
#define SINK_IT 20

typedef float f32x4 __attribute__((ext_vector_type(4)));
typedef __bf16 bf16x8 __attribute__((ext_vector_type(8)));
typedef unsigned short u16x8 __attribute__((ext_vector_type(8)));
typedef unsigned short u16x4 __attribute__((ext_vector_type(4)));

__device__ __forceinline__ unsigned short f2bf(float f) {
  unsigned u = __builtin_bit_cast(unsigned, f);
  u += 0x7FFFu + ((u >> 16) & 1u);   // round-to-nearest-even
  return (unsigned short)(u >> 16);
}
__device__ __forceinline__ float bf2f(unsigned short h) {
  return __builtin_bit_cast(float, (unsigned)h << 16);
}
__device__ __forceinline__ f32x4 bf4f(u16x4 h) {
  f32x4 r; r.x = bf2f(h[0]); r.y = bf2f(h[1]); r.z = bf2f(h[2]); r.w = bf2f(h[3]);
  return r;
}

// ---------------------------------------------------------------------------
// K0: fp32 -> bf16 for w_inner (blocks 0..8191) and hc_fn (blocks 8192..8383)
__global__ __launch_bounds__(256) void k_w2bf(const float* __restrict__ w,
                                              unsigned short* __restrict__ wb,
                                              const float* __restrict__ fn,
                                              unsigned short* __restrict__ fnb) {
  const int b = blockIdx.x;
  const float* src;
  unsigned short* dst;
  size_t i;
  if (b < 8192) { src = w; dst = wb; i = (size_t)b * 2048 + threadIdx.x * 8; }
  else { src = fn; dst = fnb; i = (size_t)(b - 8192) * 2048 + threadIdx.x * 8; }
  f32x4 a = *(const f32x4*)(src + i);
  f32x4 c = *(const f32x4*)(src + i + 4);
  u16x8 o;
  o[0] = f2bf(a.x); o[1] = f2bf(a.y); o[2] = f2bf(a.z); o[3] = f2bf(a.w);
  o[4] = f2bf(c.x); o[5] = f2bf(c.y); o[6] = f2bf(c.z); o[7] = f2bf(c.w);
  *(u16x8*)(dst + i) = o;
}

// ---------------------------------------------------------------------------
// K1 (fused): per 2 sequence-rows: mixes dots + sumsq -> gates (sigmoid +
// 20-iter Sinkhorn) -> reduced = pre.hs -> RMSNorm -> normed (bf16).
// Row cached in LDS as bf16 (64KB -> 2 blocks/CU); sumsq from fp32 values
// pre-conversion; hc_fn read as bf16 (halves the per-block L2 traffic).
// Eliminates the second full 256MB hs read of the old 3-kernel pipeline.
__global__ __launch_bounds__(256) void k_row(const float* __restrict__ hs,
                                             const unsigned short* __restrict__ fnb,
                                             const float* __restrict__ hbase,
                                             const float* __restrict__ hscale,
                                             const float* __restrict__ nw,
                                             unsigned short* __restrict__ normed,
                                             float* __restrict__ gates) {
  __shared__ __align__(16) unsigned short rowb[2][HD_DIM];   // 64KB bf16 rows
  __shared__ float smix[2][MIXN];
  __shared__ float sss[4][2];
  __shared__ float sgate[2][MIXN];
  __shared__ float sred[4];
  const int tid = threadIdx.x, lane = tid & 63, wave = tid >> 6;
  const size_t base = (size_t)blockIdx.x * 2 * HD_DIM;

  // ---- phase 1: stage rows to LDS (bf16), accumulate fp32 row-sumsq
  float ss0 = 0.f, ss1 = 0.f;
#pragma unroll
  for (int it = 0; it < 32; ++it) {
    const int fi = it * 1024 + tid * 4;       // flat index into [2][16384]
    f32x4 v = *(const f32x4*)(hs + base + fi);
    const float s2 = v.x * v.x + v.y * v.y + v.z * v.z + v.w * v.w;
    if (it < 16) ss0 += s2; else ss1 += s2;
    u16x4 o;
    o[0] = f2bf(v.x); o[1] = f2bf(v.y); o[2] = f2bf(v.z); o[3] = f2bf(v.w);
    *(u16x4*)(&rowb[0][0] + fi) = o;
  }
#pragma unroll
  for (int off = 32; off >= 1; off >>= 1) {
    ss0 += __shfl_xor(ss0, off, 64);
    ss1 += __shfl_xor(ss1, off, 64);
  }
  if (lane == 0) { sss[wave][0] = ss0; sss[wave][1] = ss1; }
  __syncthreads();

  // ---- phase 2: mix dots; wave w owns m in [6w, 6w+6)
  const int mb = wave * 6;
  float a0[6], a1[6];
#pragma unroll
  for (int j = 0; j < 6; j++) { a0[j] = 0.f; a1[j] = 0.f; }
#pragma unroll 2
  for (int it = 0; it < 64; ++it) {
    const int d = (it * 64 + lane) * 4;
    const f32x4 h0 = bf4f(*(const u16x4*)(&rowb[0][d]));
    const f32x4 h1 = bf4f(*(const u16x4*)(&rowb[1][d]));
#pragma unroll
    for (int j = 0; j < 6; j++) {
      const f32x4 fv = bf4f(*(const u16x4*)(fnb + (size_t)(mb + j) * HD_DIM + d));
      a0[j] += h0.x * fv.x + h0.y * fv.y + h0.z * fv.z + h0.w * fv.w;
      a1[j] += h1.x * fv.x + h1.y * fv.y + h1.z * fv.z + h1.w * fv.w;
    }
  }
#pragma unroll
  for (int j = 0; j < 6; j++) {
#pragma unroll
    for (int off = 32; off >= 1; off >>= 1) {
      a0[j] += __shfl_xor(a0[j], off, 64);
      a1[j] += __shfl_xor(a1[j], off, 64);
    }
    if (lane == 0) { smix[0][mb + j] = a0[j]; smix[1][mb + j] = a1[j]; }
  }
  __syncthreads();

  // ---- phase 3: gates (sigmoid + Sinkhorn), one thread per row
  if (tid < 2) {
    const int r = tid;
    const float sumsq = sss[0][r] + sss[1][r] + sss[2][r] + sss[3][r];
    const float rs = rsqrtf(sumsq * (1.0f / HD_DIM) + 1e-6f);
    const float ps = hscale[0], qs = hscale[1], cs = hscale[2];
    float g[MIXN];
#pragma unroll
    for (int m = 0; m < MIXN; m++) {
      const float sc = (m < 4) ? ps : ((m < 8) ? qs : cs);
      const float x = smix[r][m] * rs * sc + hbase[m];
      g[m] = 1.0f / (1.0f + expf(-x)) + 1e-6f;
    }
    for (int t = 0; t < SINK_IT; t++) {
#pragma unroll
      for (int i = 0; i < 4; i++) {
        const float s = g[8 + i * 4 + 0] + g[8 + i * 4 + 1] + g[8 + i * 4 + 2] + g[8 + i * 4 + 3] + 1e-6f;
#pragma unroll
        for (int j = 0; j < 4; j++) g[8 + i * 4 + j] /= s;
      }
#pragma unroll
      for (int j = 0; j < 4; j++) {
        const float s = g[8 + 0 + j] + g[8 + 4 + j] + g[8 + 8 + j] + g[8 + 12 + j] + 1e-6f;
#pragma unroll
        for (int i = 0; i < 4; i++) g[8 + i * 4 + j] /= s;
      }
    }
    float* go = gates + (size_t)(blockIdx.x * 2 + r) * MIXN;
#pragma unroll
    for (int m = 0; m < MIXN; m++) { sgate[r][m] = g[m]; go[m] = g[m]; }
  }
  __syncthreads();

  // ---- phase 4: reduced = pre.row (from LDS) -> RMS -> normed bf16
  const int r = tid >> 7;               // 0..1 (128 threads per row)
  const int dbase = (tid & 127) * 8;    // conflict-free 16B-stride-16B reads
  const float p0 = sgate[r][0], p1 = sgate[r][1], p2 = sgate[r][2], p3 = sgate[r][3];
  float red[32];
  float ssq = 0.f;
#pragma unroll
  for (int q = 0; q < 4; ++q) {
    const int d = dbase + q * 1024;
    const u16x8 va = *(const u16x8*)(&rowb[r][0 * 4096 + d]);
    const u16x8 vb = *(const u16x8*)(&rowb[r][1 * 4096 + d]);
    const u16x8 vc = *(const u16x8*)(&rowb[r][2 * 4096 + d]);
    const u16x8 vd = *(const u16x8*)(&rowb[r][3 * 4096 + d]);
#pragma unroll
    for (int k = 0; k < 8; ++k) {
      const float v = p0 * bf2f(va[k]) + p1 * bf2f(vb[k]) + p2 * bf2f(vc[k]) + p3 * bf2f(vd[k]);
      red[q * 8 + k] = v;
      ssq += v * v;
    }
  }
#pragma unroll
  for (int off = 32; off >= 1; off >>= 1) ssq += __shfl_xor(ssq, off, 64);
  if (lane == 0) sred[wave] = ssq;
  __syncthreads();
  const float tot = (r == 0) ? (sred[0] + sred[1]) : (sred[2] + sred[3]);
  const float nr = rsqrtf(tot * (1.0f / H_DIM) + 1e-6f);
  unsigned short* np = normed + (size_t)(blockIdx.x * 2 + r) * H_DIM;
#pragma unroll
  for (int q = 0; q < 4; ++q) {
    const int d = dbase + q * 1024;
    const f32x4 w0 = *(const f32x4*)(nw + d);
    const f32x4 w1 = *(const f32x4*)(nw + d + 4);
    u16x8 o;
    o[0] = f2bf(red[q * 8 + 0] * nr * w0.x); o[1] = f2bf(red[q * 8 + 1] * nr * w0.y);
    o[2] = f2bf(red[q * 8 + 2] * nr * w0.z); o[3] = f2bf(red[q * 8 + 3] * nr * w0.w);
    o[4] = f2bf(red[q * 8 + 4] * nr * w1.x); o[5] = f2bf(red[q * 8 + 5] * nr * w1.y);
    o[6] = f2bf(red[q * 8 + 6] * nr * w1.z); o[7] = f2bf(red[q * 8 + 7] * nr * w1.w);
    *(u16x8*)(np + d) = o;
  }
}

// ---------------------------------------------------------------------------
// K4: bf16 GEMM  C[s][e] = sum_d A[s][d] * B[e][d]
// 256x256 tile, 8-phase schedule (T3+T4+T5) with rule-#18 fences and the
// rule-#21 both-sides XOR bank swizzle. (Frozen this round: two schedule
// variants measured identical; see round-5 theory.)
__device__ __forceinline__ void gload_lds16(const unsigned short* g, unsigned short* l) {
  __builtin_amdgcn_global_load_lds(
      (const __attribute__((address_space(1))) unsigned int*)(const void*)g,
      (__attribute__((address_space(3))) unsigned int*)(void*)l, 16, 0, 0);
}

#define VMW(n) asm volatile("s_waitcnt vmcnt(" #n ")" ::: "memory")
#define BAR    asm volatile("s_barrier" ::: "memory")
#define LGK0   asm volatile("s_waitcnt lgkmcnt(0)" ::: "memory")
#define SCB    __builtin_amdgcn_sched_barrier(0)

__global__ __launch_bounds__(512, 2) void k_gemm(const unsigned short* __restrict__ A,
                                                 const unsigned short* __restrict__ B,
                                                 unsigned short* __restrict__ C) {
  __shared__ __align__(16) unsigned short sAbuf[2][2][256 * 32];
  __shared__ __align__(16) unsigned short sBbuf[2][2][256 * 32];
  const int tid = threadIdx.x;
  const int lane = tid & 63, wave = tid >> 6;

  // Bijective XCD swizzle (256 blocks % 8 == 0): XCD v owns bn in {2v,2v+1}.
  const int bid = blockIdx.x;
  const int v = bid & 7, u = bid >> 3;          // u in 0..31
  const int bm = u & 15, bn = v * 2 + (u >> 4);
  const int wm = wave >> 2, wn = wave & 3;      // 2x4 wave grid, 128x64 per wave

  // staging: wave stages rows [wave*32, +32) of a [256][32] k-half, 2 instr.
  // Pre-swizzled global source: chunk = (lane&3) ^ (row&3), row = lane>>2.
  const int srow = lane >> 2;                              // 0..15
  const int sk8 = (((lane & 3) ^ ((lane >> 2) & 3)) * 8);  // swizzled k-offset
  const unsigned short* gA = A + (size_t)(bm * 256 + wave * 32 + srow) * 4096 + sk8;
  const unsigned short* gB = B + (size_t)(bn * 256 + wave * 32 + srow) * 4096 + sk8;
  const int ld0 = wave * 1024 + lane * 8;   // element offset, instr 0 (linear dest)
  const int ld1 = ld0 + 512;                // rows +16..31

  f32x4 acc[8][4];
  f32x4 zero = {0.f, 0.f, 0.f, 0.f};
#pragma unroll
  for (int mf = 0; mf < 8; mf++)
#pragma unroll
    for (int nf = 0; nf < 4; nf++) acc[mf][nf] = zero;
  bf16x8 af[8];

  // fragment read: logical chunk = lane>>4, row&3 = lane&3 (row bases %4==0)
  const int frow = lane & 15;
  const int fk = (((lane >> 4) ^ (lane & 3)) * 8);   // swizzled read offset

#define PHASE_BODY(db, kh, nh, dostg, sdst, gsrc, t, skh) do {                  \
    if ((nh) == 0) {                                                            \
      _Pragma("unroll") for (int mf = 0; mf < 8; mf++)                          \
        af[mf] = *(const bf16x8*)&sAbuf[db][kh][(wm * 128 + mf * 16 + frow) * 32 + fk]; \
    }                                                                           \
    bf16x8 b0 = *(const bf16x8*)&sBbuf[db][kh][(wn * 64 + ((nh) * 2 + 0) * 16 + frow) * 32 + fk]; \
    bf16x8 b1 = *(const bf16x8*)&sBbuf[db][kh][(wn * 64 + ((nh) * 2 + 1) * 16 + frow) * 32 + fk]; \
    if (dostg) {                                                                \
      const unsigned short* _g = (gsrc) + (size_t)(t) * 64 + (skh) * 32;        \
      gload_lds16(_g,              (sdst) + ld0);                               \
      gload_lds16(_g + 16 * 4096,  (sdst) + ld1);                               \
    }                                                                           \
    SCB;                                                                        \
    BAR;                                                                        \
    LGK0;                                                                       \
    SCB;                                                                        \
    __builtin_amdgcn_s_setprio(1);                                              \
    _Pragma("unroll") for (int mf = 0; mf < 8; mf++) {                          \
      acc[mf][(nh) * 2 + 0] = __builtin_amdgcn_mfma_f32_16x16x32_bf16(af[mf], b0, acc[mf][(nh) * 2 + 0], 0, 0, 0); \
      acc[mf][(nh) * 2 + 1] = __builtin_amdgcn_mfma_f32_16x16x32_bf16(af[mf], b1, acc[mf][(nh) * 2 + 1], 0, 0, 0); \
    }                                                                           \
    __builtin_amdgcn_s_setprio(0);                                              \
    SCB;                                                                        \
  } while (0)

  // prologue: tile 0 -> db0 in order A-kh0, B-kh0, A-kh1, B-kh1
  gload_lds16(gA,                  &sAbuf[0][0][0] + ld0);
  gload_lds16(gA + 16 * 4096,      &sAbuf[0][0][0] + ld1);
  gload_lds16(gB,                  &sBbuf[0][0][0] + ld0);
  gload_lds16(gB + 16 * 4096,      &sBbuf[0][0][0] + ld1);
  gload_lds16(gA + 32,             &sAbuf[0][1][0] + ld0);
  gload_lds16(gA + 32 + 16 * 4096, &sAbuf[0][1][0] + ld1);
  gload_lds16(gB + 32,             &sBbuf[0][1][0] + ld0);
  gload_lds16(gB + 32 + 16 * 4096, &sBbuf[0][1][0] + ld1);
  VMW(4);   // A-kh0, B-kh0 of tile 0 arrived
  BAR;

  for (int i = 0; i < 31; ++i) {
    const int t1 = 2 * i + 1, t2 = 2 * i + 2;
    PHASE_BODY(0, 0, 0, 1, &sAbuf[1][0][0], gA, t1, 0);          BAR;
    PHASE_BODY(0, 0, 1, 1, &sBbuf[1][0][0], gB, t1, 0); VMW(4);  BAR;
    PHASE_BODY(0, 1, 0, 1, &sAbuf[1][1][0], gA, t1, 1);          BAR;
    PHASE_BODY(0, 1, 1, 1, &sBbuf[1][1][0], gB, t1, 1); VMW(4);  BAR;
    PHASE_BODY(1, 0, 0, 1, &sAbuf[0][0][0], gA, t2, 0);          BAR;
    PHASE_BODY(1, 0, 1, 1, &sBbuf[0][0][0], gB, t2, 0); VMW(4);  BAR;
    PHASE_BODY(1, 1, 0, 1, &sAbuf[0][1][0], gA, t2, 1);          BAR;
    PHASE_BODY(1, 1, 1, 1, &sBbuf[0][1][0], gB, t2, 1); VMW(4);  BAR;
  }
  // peeled last iteration (i = 31): stage tile 63 only; drain with vmcnt(0)
  PHASE_BODY(0, 0, 0, 1, &sAbuf[1][0][0], gA, 63, 0);            BAR;
  PHASE_BODY(0, 0, 1, 1, &sBbuf[1][0][0], gB, 63, 0); VMW(4);    BAR;
  PHASE_BODY(0, 1, 0, 1, &sAbuf[1][1][0], gA, 63, 1);            BAR;
  PHASE_BODY(0, 1, 1, 1, &sBbuf[1][1][0], gB, 63, 1); VMW(0);    BAR;
  PHASE_BODY(1, 0, 0, 0, &sAbuf[0][0][0], gA, 0, 0);             BAR;
  PHASE_BODY(1, 0, 1, 0, &sAbuf[0][0][0], gA, 0, 0);             BAR;
  PHASE_BODY(1, 1, 0, 0, &sAbuf[0][0][0], gA, 0, 0);             BAR;
  PHASE_BODY(1, 1, 1, 0, &sAbuf[0][0][0], gA, 0, 0);

#undef PHASE_BODY

  // epilogue: C write (bf16)
  const int crow0 = bm * 256 + wm * 128 + (lane >> 4) * 4;
  const int ccol0 = bn * 256 + wn * 64 + (lane & 15);
#pragma unroll
  for (int mf = 0; mf < 8; mf++)
#pragma unroll
    for (int nf = 0; nf < 4; nf++)
#pragma unroll
      for (int j = 0; j < 4; j++)
        C[(size_t)(crow0 + mf * 16 + j) * 4096 + ccol0 + nf * 16] = f2bf(acc[mf][nf][j]);
}

// ---------------------------------------------------------------------------
// K5: expanded[s][h][d] = post[h]*out[s][d] + sum_k comb[h][k]*hs[s][k][d]
__global__ __launch_bounds__(256) void k_expand(const float* __restrict__ hs,
                                                const unsigned short* __restrict__ outb,
                                                const float* __restrict__ gates,
                                                float* __restrict__ y) {
  const int s = blockIdx.x, tid = threadIdx.x;
  const float* g = gates + (size_t)s * MIXN;
  float post[4], cb[4][4];
#pragma unroll
  for (int h = 0; h < 4; h++) post[h] = g[4 + h];
#pragma unroll
  for (int h = 0; h < 4; h++)
#pragma unroll
    for (int k = 0; k < 4; k++) cb[h][k] = g[8 + h * 4 + k];

  const size_t base = (size_t)s * HC_N * H_DIM;
#pragma unroll
  for (int it = 0; it < 4; ++it) {
    const int d4 = it * 256 + tid;
    f32x4 hv[4];
#pragma unroll
    for (int k = 0; k < 4; k++)
      hv[k] = *(const f32x4*)(hs + base + (size_t)k * H_DIM + (size_t)d4 * 4);
    u16x4 ob = *(const u16x4*)(outb + (size_t)s * H_DIM + (size_t)d4 * 4);
    f32x4 o = {bf2f(ob[0]), bf2f(ob[1]), bf2f(ob[2]), bf2f(ob[3])};
#pragma unroll
    for (int h = 0; h < 4; h++) {
      f32x4 e = post[h] * o + cb[h][0] * hv[0] + cb[h][1] * hv[1] + cb[h][2] * hv[2] + cb[h][3] * hv[3];
      *(f32x4*)(y + base + (size_t)h * H_DIM + (size_t)d4 * 4) = e;
    }
  }
}

// ---------------------------------------------------------------------------
extern "C" void kernel_launch(void* const* d_in, const int* in_sizes, int n_in,
                              void* d_out, int out_size, void* d_ws, size_t ws_size,
                              hipStream_t stream) {
  const float* hs = (const float*)d_in[0];      // [1,4096,4,4096]
  const float* fn = (const float*)d_in[1];      // [24,16384]
  const float* hbase = (const float*)d_in[2];   // [24]
  const float* hscale = (const float*)d_in[3];  // [3]
  const float* nw = (const float*)d_in[4];      // [4096]
  const float* wi = (const float*)d_in[5];      // [4096,4096]
  float* y = (float*)d_out;                     // [1,4096,4,4096] fp32

  char* ws = (char*)d_ws;
  float* gates = (float*)(ws);                                          // 393216 B
  unsigned short* normed = (unsigned short*)(ws + 1048576);             // 32MB bf16
  unsigned short* wb = (unsigned short*)(ws + 1048576 + 33554432);      // 32MB bf16
  unsigned short* outb = (unsigned short*)(ws + 1048576 + 2 * 33554432);// 32MB bf16
  // fnb (0.75MB) aliases the head of outb: k_w2bf writes it, k_row reads it,
  // then k_gemm overwrites the region with outb (strictly later in-stream).
  unsigned short* fnb = outb;
  // total ws use: ~97MB (unchanged)

  k_w2bf<<<8384, 256, 0, stream>>>(wi, wb, fn, fnb);
  k_row<<<2048, 256, 0, stream>>>(hs, fnb, hbase, hscale, nw, normed, gates);
  k_gemm<<<256, 512, 0, stream>>>(normed, wb, outb);
  k_expand<<<4096, 256, 0, stream>>>(hs, outb, gates, y);
}